// Round 11
// baseline (100.249 us; speedup 1.0000x reference)
//
#include <hip/hip_runtime.h>

#define POOL 7
#define CCH 256
#define GCH 4             // channels per block (= waves per block)
#define HH 100
#define WW 100
#define HW (HH * WW)
#define MAXTH 28          // worst-case row span (<=27)
#define NTAP 14           // POOL * NSAMP samples per axis
#define RECI 128          // ints per ROI record
#define NT 256

static constexpr float SCALE = 0.125f;

__device__ __attribute__((aligned(16))) int g_rec[1024 * RECI];  // ws fallback

__device__ __forceinline__ void tap_calc(float s0, float step, int k, int L,
                                         int& lo, int& hi, float& w1, float& w2)
{
    const int   p  = k >> 1, si = k & 1;
    const float g  = (float)p + ((float)si + 0.5f) * 0.5f;
    const float c  = s0 + g * step;
    const float Lf = (float)L;
    const bool  valid = (c > -1.0f) && (c < Lf);
    float cl = fminf(fmaxf(c, 0.0f), Lf - 1.0f);
    lo = (int)floorf(cl);
    if (lo > L - 1) lo = L - 1;
    hi = lo + 1;
    if (hi > L - 1) hi = L - 1;
    const float fr = cl - (float)lo;
    w1 = valid ? 1.0f - fr : 0.0f;
    w2 = valid ? fr : 0.0f;
}

// Per ROI: {n, xmin_al, ymin, TH} + 28 taps (tile-relative, monotonic).
__global__ __launch_bounds__(64) void roi_pre(const float* __restrict__ rois,
                                              int* __restrict__ rec, int R)
{
    const int r = blockIdx.x;
    if (r >= R) return;
    int* rr = (rec ? rec : g_rec) + r * RECI;
    const int t = threadIdx.x;

    const float sx0 = rois[r * 5 + 1] * SCALE - 0.5f;
    const float sy0 = rois[r * 5 + 2] * SCALE - 0.5f;
    const float bw  = (rois[r * 5 + 3] * SCALE - 0.5f - sx0) * (1.0f / POOL);
    const float bh  = (rois[r * 5 + 4] * SCALE - 0.5f - sy0) * (1.0f / POOL);

    if (t < 2 * NTAP) {
        const int   axis = (t >= NTAP) ? 1 : 0;
        const int   k    = axis ? t - NTAP : t;
        const float s0   = axis ? sy0 : sx0;
        const float st   = axis ? bh : bw;
        const int   L    = axis ? HH : WW;
        int lo, hi, lo0, u0; float w1, w2, ua, ub;
        tap_calc(s0, st, k, L, lo, hi, w1, w2);
        tap_calc(s0, st, 0, L, lo0, u0, ua, ub);
        const int base = axis ? lo0 : (lo0 & ~3);
        int* tp = rr + 8 + (axis ? 4 * NTAP : 0) + k * 4;
        tp[0] = max(lo - base, 0);
        tp[1] = max(hi - base, 0);
        tp[2] = __float_as_int(w1);
        tp[3] = __float_as_int(w2);
    } else if (t == 2 * NTAP) {
        int xl0, xh0, yl0, yh0, yl13, yh13; float a, b;
        tap_calc(sx0, bw, 0,        WW, xl0,  xh0,  a, b);
        tap_calc(sy0, bh, 0,        HH, yl0,  yh0,  a, b);
        tap_calc(sy0, bh, NTAP - 1, HH, yl13, yh13, a, b);
        const int xmin_al = xl0 & ~3;
        int TH  = yh13 - yl0 + 1; if (TH > MAXTH) TH = MAXTH;
        rr[0] = (int)rois[r * 5 + 0];
        rr[1] = xmin_al;
        rr[2] = yl0;
        rr[3] = TH;
    }
}

// Direct register gather: thread = (channel, bin), 16 global loads straight
// from NCHW into registers. No LDS, no DMA, no barrier. Chunked XCD swizzle
// keeps one ROI's 64 blocks on one XCD's L2.
__global__ __launch_bounds__(NT) void roi_main(
    const float* __restrict__ x, const int* __restrict__ rec_in,
    float* __restrict__ out, int nwg)
{
    const int bid  = blockIdx.x;
    const int swb  = ((nwg & 7) == 0)
                   ? ((bid & 7) * (nwg >> 3) + (bid >> 3)) : bid;
    const int r    = swb >> 6;                    // 64 blocks per ROI
    const int c0   = (swb & 63) * GCH;
    const int t    = threadIdx.x;
    const int ch   = t >> 6;                      // 0..3
    const int lane = t & 63;

    const int* rr = (rec_in ? rec_in : g_rec) + r * RECI;
    const int n       = rr[0];
    const int xmin_al = rr[1];
    const int ymin    = rr[2];

    const int bin = (lane < POOL * POOL) ? lane : POOL * POOL - 1;
    const int py  = bin / POOL;
    const int px  = bin - py * POOL;

    const int4* tp = (const int4*)(rr + 8);
    const int4 xt0 = tp[px * 2],        xt1 = tp[px * 2 + 1];
    const int4 yt0 = tp[NTAP + py * 2], yt1 = tp[NTAP + py * 2 + 1];

    // base points at (row ymin, col xmin_al) of this thread's channel;
    // taps are tile-relative so addr = base + ytrel*WW + xtrel.
    const float* base = x + ((size_t)(n * CCH + c0 + ch)) * HW
                          + (size_t)ymin * WW + xmin_al;

    const int rl0 = yt0.x * WW, rh0 = yt0.y * WW;
    const int rl1 = yt1.x * WW, rh1 = yt1.y * WW;

    // 16 independent loads — issue all, then combine (MLP-deep).
    const float v00 = base[rl0 + xt0.x];
    const float v01 = base[rl0 + xt0.y];
    const float v02 = base[rh0 + xt0.x];
    const float v03 = base[rh0 + xt0.y];
    const float v04 = base[rl0 + xt1.x];
    const float v05 = base[rl0 + xt1.y];
    const float v06 = base[rh0 + xt1.x];
    const float v07 = base[rh0 + xt1.y];
    const float v08 = base[rl1 + xt0.x];
    const float v09 = base[rl1 + xt0.y];
    const float v10 = base[rh1 + xt0.x];
    const float v11 = base[rh1 + xt0.y];
    const float v12 = base[rl1 + xt1.x];
    const float v13 = base[rl1 + xt1.y];
    const float v14 = base[rh1 + xt1.x];
    const float v15 = base[rh1 + xt1.y];

    const float wy10 = __int_as_float(yt0.z), wy20 = __int_as_float(yt0.w);
    const float wy11 = __int_as_float(yt1.z), wy21 = __int_as_float(yt1.w);
    const float wx10 = __int_as_float(xt0.z), wx20 = __int_as_float(xt0.w);
    const float wx11 = __int_as_float(xt1.z), wx21 = __int_as_float(xt1.w);

    float acc;
    acc  = wy10 * (wx10 * v00 + wx20 * v01) + wy20 * (wx10 * v02 + wx20 * v03);
    acc += wy10 * (wx11 * v04 + wx21 * v05) + wy20 * (wx11 * v06 + wx21 * v07);
    acc += wy11 * (wx10 * v08 + wx20 * v09) + wy21 * (wx10 * v10 + wx20 * v11);
    acc += wy11 * (wx11 * v12 + wx21 * v13) + wy21 * (wx11 * v14 + wx21 * v15);

    if (lane < POOL * POOL)
        out[(size_t)(r * CCH + c0 + ch) * (POOL * POOL) + bin] = acc * 0.25f;
}

extern "C" void kernel_launch(void* const* d_in, const int* in_sizes, int n_in,
                              void* d_out, int out_size, void* d_ws, size_t ws_size,
                              hipStream_t stream) {
    const float* x    = (const float*)d_in[0];
    const float* rois = (const float*)d_in[1];
    float*       out  = (float*)d_out;

    const int R = in_sizes[1] / 5;
    int* rec = (ws_size >= (size_t)R * RECI * sizeof(int)) ? (int*)d_ws : nullptr;

    const int nwg = R * (CCH / GCH);              // 64 blocks per ROI

    roi_pre<<<R, 64, 0, stream>>>(rois, rec, R);
    roi_main<<<nwg, NT, 0, stream>>>(x, rec, out, nwg);
}

// Round 12
// 36.527 us; speedup vs baseline: 2.7445x; 2.7445x over previous
//
#include <hip/hip_runtime.h>

#define POOL 7
#define CCH 256
#define HH 100
#define WW 100
#define HW (HH * WW)
#define MAXTH 28          // worst-case row span (<=27)
#define NTAP 14           // POOL * NSAMP samples per axis
#define NT 256            // 4 waves per block
#define ITEMS 2           // channels per wave
#define SLOTF 896         // floats per LDS slot = MAXTH*8blocks*4 (3584 B)

static constexpr float SCALE = 0.125f;

// lo/hi/w1/w2 for sample k (0..13) along one axis.
__device__ __forceinline__ void tap_calc(float s0, float step, int k, int L,
                                         int& lo, int& hi, float& w1, float& w2)
{
    const int   p  = k >> 1, si = k & 1;
    const float g  = (float)p + ((float)si + 0.5f) * 0.5f;
    const float c  = s0 + g * step;
    const float Lf = (float)L;
    const bool  valid = (c > -1.0f) && (c < Lf);
    float cl = fminf(fmaxf(c, 0.0f), Lf - 1.0f);
    lo = (int)floorf(cl);
    if (lo > L - 1) lo = L - 1;
    hi = lo + 1;
    if (hi > L - 1) hi = L - 1;
    const float fr = cl - (float)lo;
    w1 = valid ? 1.0f - fr : 0.0f;
    w2 = valid ? fr : 0.0f;
}

// Per-wave pipeline over 2 channels of one ROI (R10 structure), with the
// per-ROI tap/bbox math fused in (no pre-kernel, no workspace round-trip).
// Issue order: [DMA A0,B0,A1,B1,...] -> vmcnt(1) -> compute A -> vmcnt(0)
// -> compute B. Compile-time NJ, exec-masked last iteration.
template <int NJ>
__device__ __forceinline__ void run2(
    const float* __restrict__ x, float* __restrict__ out,
    float* slot, int n, int c0, int r, int xmin_al, int ymin,
    int TWp, int tot, int magic, int nb4, int lane,
    const int4& xt0, const int4& xt1, const int4& yt0, const int4& yt1,
    int bin)
{
    const float* xa = x + ((size_t)(n * CCH + c0)) * HW
                        + (size_t)ymin * WW + xmin_al;
    const float* xb = xa + HW;           // channel c0+1

    #pragma unroll
    for (int j = 0; j < NJ; ++j) {
        const int idx = lane + 64 * j;
        const int row = (idx * magic) >> 16;
        const int b   = idx - row * nb4;
        const int go  = row * WW + (b << 2);       // floats
        float* la = slot + j * 256;                // 64 lanes * 4 floats
        float* lb = slot + SLOTF + j * 256;
        if (j < NJ - 1 || idx < tot) {             // mask last iteration
            __builtin_amdgcn_global_load_lds(
                (const __attribute__((address_space(1))) void*)(xa + go),
                (__attribute__((address_space(3))) void*)la, 16, 0, 0);
            __builtin_amdgcn_global_load_lds(
                (const __attribute__((address_space(1))) void*)(xb + go),
                (__attribute__((address_space(3))) void*)lb, 16, 0, 0);
        }
    }

    // ---- off/wgt precompute (overlaps DMA latency) ----
    int   off[16];
    float wgt[16];
    {
        const int   rl0 = yt0.x * TWp, rh0 = yt0.y * TWp;
        const int   rl1 = yt1.x * TWp, rh1 = yt1.y * TWp;
        const float wy10 = __int_as_float(yt0.z), wy20 = __int_as_float(yt0.w);
        const float wy11 = __int_as_float(yt1.z), wy21 = __int_as_float(yt1.w);
        const float wx10 = __int_as_float(xt0.z), wx20 = __int_as_float(xt0.w);
        const float wx11 = __int_as_float(xt1.z), wx21 = __int_as_float(xt1.w);
        off[0]  = rl0 + xt0.x;  wgt[0]  = wy10 * wx10;
        off[1]  = rl0 + xt0.y;  wgt[1]  = wy10 * wx20;
        off[2]  = rh0 + xt0.x;  wgt[2]  = wy20 * wx10;
        off[3]  = rh0 + xt0.y;  wgt[3]  = wy20 * wx20;
        off[4]  = rl0 + xt1.x;  wgt[4]  = wy10 * wx11;
        off[5]  = rl0 + xt1.y;  wgt[5]  = wy10 * wx21;
        off[6]  = rh0 + xt1.x;  wgt[6]  = wy20 * wx11;
        off[7]  = rh0 + xt1.y;  wgt[7]  = wy20 * wx21;
        off[8]  = rl1 + xt0.x;  wgt[8]  = wy11 * wx10;
        off[9]  = rl1 + xt0.y;  wgt[9]  = wy11 * wx20;
        off[10] = rh1 + xt0.x;  wgt[10] = wy21 * wx10;
        off[11] = rh1 + xt0.y;  wgt[11] = wy21 * wx20;
        off[12] = rl1 + xt1.x;  wgt[12] = wy11 * wx11;
        off[13] = rl1 + xt1.y;  wgt[13] = wy11 * wx21;
        off[14] = rh1 + xt1.x;  wgt[14] = wy21 * wx11;
        off[15] = rh1 + xt1.y;  wgt[15] = wy21 * wx21;
    }

    asm volatile("s_waitcnt vmcnt(1)" ::: "memory");   // channel A resident
    float a0 = 0.f, a1 = 0.f, a2 = 0.f, a3 = 0.f;
    #pragma unroll
    for (int i = 0; i < 16; i += 4) {
        a0 += wgt[i + 0] * slot[off[i + 0]];
        a1 += wgt[i + 1] * slot[off[i + 1]];
        a2 += wgt[i + 2] * slot[off[i + 2]];
        a3 += wgt[i + 3] * slot[off[i + 3]];
    }
    const float accA = (a0 + a1) + (a2 + a3);

    asm volatile("s_waitcnt vmcnt(0)" ::: "memory");   // channel B resident
    const float* sb = slot + SLOTF;
    float b0 = 0.f, b1 = 0.f, b2 = 0.f, b3 = 0.f;
    #pragma unroll
    for (int i = 0; i < 16; i += 4) {
        b0 += wgt[i + 0] * sb[off[i + 0]];
        b1 += wgt[i + 1] * sb[off[i + 1]];
        b2 += wgt[i + 2] * sb[off[i + 2]];
        b3 += wgt[i + 3] * sb[off[i + 3]];
    }
    const float accB = (b0 + b1) + (b2 + b3);

    if (lane < POOL * POOL) {
        float* ob = out + ((size_t)(r * CCH + c0)) * (POOL * POOL) + bin;
        ob[0]           = accA * 0.25f;
        ob[POOL * POOL] = accB * 0.25f;
    }
}

// Single fused kernel: one block = 4 waves = 8 channels of one ROI.
__global__ __launch_bounds__(NT) void roi_main(
    const float* __restrict__ x, const float* __restrict__ rois,
    float* __restrict__ out)
{
    __shared__ float tile[(NT / 64) * ITEMS * SLOTF];   // 28672 B

    const int bid  = blockIdx.x;
    const int r    = bid >> 5;                 // 32 groups per ROI
    const int g    = bid & 31;
    const int wid  = threadIdx.x >> 6;
    const int lane = threadIdx.x & 63;
    const int c0   = g * (ITEMS * NT / 64) + wid * ITEMS;

    // ---- per-ROI params (L2-hot broadcast reads) ----
    const float r0  = rois[r * 5 + 0];
    const float sx0 = rois[r * 5 + 1] * SCALE - 0.5f;
    const float sy0 = rois[r * 5 + 2] * SCALE - 0.5f;
    const float bw  = (rois[r * 5 + 3] * SCALE - 0.5f - sx0) * (1.0f / POOL);
    const float bh  = (rois[r * 5 + 4] * SCALE - 0.5f - sy0) * (1.0f / POOL);
    const int   n   = (int)r0;

    // ---- bbox (taps monotonic: bounds from samples 0 and 13) ----
    int xl0, xh0, xl13, xh13, yl0d, yh0d, yl13, yh13; float ua, ub;
    tap_calc(sx0, bw, 0,        WW, xl0,  xh0,  ua, ub);
    tap_calc(sx0, bw, NTAP - 1, WW, xl13, xh13, ua, ub);
    tap_calc(sy0, bh, 0,        HH, yl0d, yh0d, ua, ub);
    tap_calc(sy0, bh, NTAP - 1, HH, yl13, yh13, ua, ub);
    const int xmin_al = xl0 & ~3;
    const int ymin    = yl0d;
    int TH  = yh13 - ymin + 1; if (TH > MAXTH) TH = MAXTH;
    int nb4 = ((xh13 - xmin_al) >> 2) + 1;  if (nb4 > 8) nb4 = 8;
    const int magic = (int)ceilf(65536.0f / (float)nb4);
    const int tot   = TH * nb4;
    const int TWp   = nb4 << 2;
    const int nj    = (tot + 63) >> 6;         // 1..4

    // ---- this lane's 4 tap records (tile-relative, clamped) ----
    const int bin = (lane < POOL * POOL) ? lane : POOL * POOL - 1;
    const int py  = bin / POOL;
    const int px  = bin - py * POOL;

    int4 xt0, xt1, yt0, yt1;
    {
        int lo, hi; float w1, w2;
        tap_calc(sx0, bw, px * 2,     WW, lo, hi, w1, w2);
        xt0 = make_int4(max(lo - xmin_al, 0), max(hi - xmin_al, 0),
                        __float_as_int(w1), __float_as_int(w2));
        tap_calc(sx0, bw, px * 2 + 1, WW, lo, hi, w1, w2);
        xt1 = make_int4(max(lo - xmin_al, 0), max(hi - xmin_al, 0),
                        __float_as_int(w1), __float_as_int(w2));
        tap_calc(sy0, bh, py * 2,     HH, lo, hi, w1, w2);
        yt0 = make_int4(max(lo - ymin, 0), max(hi - ymin, 0),
                        __float_as_int(w1), __float_as_int(w2));
        tap_calc(sy0, bh, py * 2 + 1, HH, lo, hi, w1, w2);
        yt1 = make_int4(max(lo - ymin, 0), max(hi - ymin, 0),
                        __float_as_int(w1), __float_as_int(w2));
    }

    float* slot = tile + wid * (ITEMS * SLOTF);

    switch (nj) {
    case 1:  run2<1>(x, out, slot, n, c0, r, xmin_al, ymin, TWp, tot, magic, nb4, lane, xt0, xt1, yt0, yt1, bin); break;
    case 2:  run2<2>(x, out, slot, n, c0, r, xmin_al, ymin, TWp, tot, magic, nb4, lane, xt0, xt1, yt0, yt1, bin); break;
    case 3:  run2<3>(x, out, slot, n, c0, r, xmin_al, ymin, TWp, tot, magic, nb4, lane, xt0, xt1, yt0, yt1, bin); break;
    default: run2<4>(x, out, slot, n, c0, r, xmin_al, ymin, TWp, tot, magic, nb4, lane, xt0, xt1, yt0, yt1, bin); break;
    }
}

extern "C" void kernel_launch(void* const* d_in, const int* in_sizes, int n_in,
                              void* d_out, int out_size, void* d_ws, size_t ws_size,
                              hipStream_t stream) {
    const float* x    = (const float*)d_in[0];
    const float* rois = (const float*)d_in[1];
    float*       out  = (float*)d_out;

    const int R = in_sizes[1] / 5;
    roi_main<<<R * 32, NT, 0, stream>>>(x, rois, out);
}